// Round 2
// baseline (95951.947 us; speedup 1.0000x reference)
//
#include <hip/hip_runtime.h>

// ---------------- problem constants ----------------
constexpr int SEQ = 2048;
constexpr int HD  = 512;     // H = D = DW
constexpr int TH3 = 1536;    // 3H
constexpr int ZT  = 3072;    // combined [W_hh | Ww_hh] output cols
constexpr int KWW = 3;

constexpr int GRID = 128;    // scan blocks
constexpr int NT   = 256;    // scan threads/block
constexpr int ZB   = ZT / GRID;   // 24 z-cols per block
constexpr int HB   = HD / GRID;   // 4 h per block

// ws layout (bytes)
constexpr size_t WS_LEAF   = 0;          // 8 leaf counters, 256B apart
constexpr size_t WS_ROOT   = 2048;
constexpr size_t WS_FLAG   = 2304;       // dtype-detect count
constexpr size_t WS_Z      = 4096;       // 3072 f32
constexpr size_t WS_CS0    = 16384;      // c_state ping
constexpr size_t WS_CS1    = 18432;      // c_state pong
constexpr size_t WS_HSTATE = 20480;      // 512 f32
constexpr size_t WS_ZEROSZ = 22528;      // memset region
constexpr size_t WS_WIB    = 32768;                       // 2048*1536 f32
constexpr size_t WS_AWIB   = WS_WIB  + (size_t)SEQ*TH3*4; // 2048*512 f32
constexpr size_t WS_WWIB   = WS_AWIB + (size_t)SEQ*HD*4;  // 6144*1536 f32
constexpr size_t WS_CBUF   = WS_WWIB + (size_t)SEQ*KWW*TH3*4; // 6144*512 f32
constexpr size_t WS_END    = WS_CBUF + (size_t)SEQ*KWW*HD*4;

__device__ inline float bf2f(unsigned int u) {
    return __builtin_bit_cast(float, u << 16);
}
__device__ inline unsigned short f2bf(float f) {
    unsigned int u = __builtin_bit_cast(unsigned int, f);
    u += 0x7fffu + ((u >> 16) & 1u);   // RNE
    return (unsigned short)(u >> 16);
}
__device__ inline float sigf(float x) { return 1.0f / (1.0f + expf(-x)); }

// dual-dtype loads: mode=1 -> bf16 storage, mode=0 -> f32 storage
__device__ inline float4 ld4e(const void* p, size_t eoff, int mode) {
    if (mode) {
        uint2 v = *(const uint2*)((const unsigned short*)p + eoff);
        return make_float4(bf2f(v.x & 0xffffu), bf2f(v.x >> 16),
                           bf2f(v.y & 0xffffu), bf2f(v.y >> 16));
    }
    return *(const float4*)((const float*)p + eoff);
}
__device__ inline float ld1e(const void* p, size_t eoff, int mode) {
    return mode ? bf2f((unsigned int)((const unsigned short*)p)[eoff])
                : ((const float*)p)[eoff];
}

// ---------------- dtype detection ----------------
// If W_ih is packed bf16, the low 16 bits of each 32-bit word are a full bf16
// value of a ~N(0, 1/sqrt(512)) sample -> exponent field in [100,127] nearly
// always. If f32, those bits are mantissa noise -> ~20% hit rate.
constexpr int NDET = 4096;
__global__ void detect_kernel(const unsigned int* __restrict__ w, int* __restrict__ cnt) {
    int local = 0;
    for (int i = threadIdx.x; i < NDET; i += 256) {
        unsigned int e = (w[i] >> 7) & 0xffu;
        if (e >= 90u && e <= 140u) local++;
    }
    atomicAdd(cnt, local);
}

// ---------------- precompute GEMM: C[M,N] = gather(A)[M,K] @ B[K,N] + bias ----------------
template<bool GATHER>
__global__ __launch_bounds__(256) void gemm_bias_kernel(
    const void* __restrict__ A, const void* __restrict__ B,
    const void* __restrict__ bias, const int* __restrict__ ids,
    const int* __restrict__ cnt,
    float* __restrict__ C, int M, int N, int K)
{
    const int mode = (*cnt > NDET / 2) ? 1 : 0;
    __shared__ __align__(16) float As[16][68];
    __shared__ __align__(16) float Bs[16][68];
    const int tid = threadIdx.x;
    const int ty = tid >> 4, tx = tid & 15;
    const int m0 = blockIdx.y * 64, n0 = blockIdx.x * 64;
    const int lrow = tid >> 2;            // 0..63
    const int kq   = (tid & 3) * 4;       // 0,4,8,12
    const int arow = m0 + lrow;
    const size_t abase = (GATHER ? (size_t)ids[arow] : (size_t)arow) * (size_t)K;
    const int brow = tid >> 4;            // 0..15
    const int bc   = (tid & 15) * 4;
    const int bcol = n0 + bc;
    float acc[4][4] = {};
    for (int k0 = 0; k0 < K; k0 += 16) {
        float4 av = ld4e(A, abase + k0 + kq, mode);
        float4 bv = ld4e(B, (size_t)(k0 + brow) * N + bcol, mode);
        As[kq + 0][lrow] = av.x;
        As[kq + 1][lrow] = av.y;
        As[kq + 2][lrow] = av.z;
        As[kq + 3][lrow] = av.w;
        Bs[brow][bc + 0] = bv.x;
        Bs[brow][bc + 1] = bv.y;
        Bs[brow][bc + 2] = bv.z;
        Bs[brow][bc + 3] = bv.w;
        __syncthreads();
        #pragma unroll
        for (int kk = 0; kk < 16; ++kk) {
            float a[4], bb[4];
            #pragma unroll
            for (int u = 0; u < 4; ++u) a[u] = As[kk][ty * 4 + u];
            #pragma unroll
            for (int v = 0; v < 4; ++v) bb[v] = Bs[kk][tx * 4 + v];
            #pragma unroll
            for (int u = 0; u < 4; ++u)
                #pragma unroll
                for (int v = 0; v < 4; ++v)
                    acc[u][v] = fmaf(a[u], bb[v], acc[u][v]);
        }
        __syncthreads();
    }
    float4 bsv = ld4e(bias, (size_t)(n0 + tx * 4), mode);
    #pragma unroll
    for (int u = 0; u < 4; ++u) {
        float4 o;
        o.x = acc[u][0] + bsv.x; o.y = acc[u][1] + bsv.y;
        o.z = acc[u][2] + bsv.z; o.w = acc[u][3] + bsv.w;
        *(float4*)(C + (size_t)(m0 + ty * 4 + u) * N + n0 + tx * 4) = o;
    }
}

// ---------------- two-level device barrier ----------------
__device__ inline void gbar(int* leaf, int* root, int b, int k) {
    __threadfence();
    __syncthreads();
    if (threadIdx.x == 0) {
        int lv = __hip_atomic_fetch_add(&leaf[(b & 7) * 64], 1,
                     __ATOMIC_ACQ_REL, __HIP_MEMORY_SCOPE_AGENT) + 1;
        if (lv == 16 * k)
            __hip_atomic_fetch_add(root, 1, __ATOMIC_ACQ_REL, __HIP_MEMORY_SCOPE_AGENT);
        while (__hip_atomic_load(root, __ATOMIC_ACQUIRE, __HIP_MEMORY_SCOPE_AGENT) < 8 * k)
            __builtin_amdgcn_s_sleep(2);
    }
    __syncthreads();
    __threadfence();
}

// ---------------- persistent sequential scan ----------------
__global__ __launch_bounds__(NT, 1) void lattice_scan(
    const void* __restrict__ W_hh, const void* __restrict__ Ww_hh,
    const void* __restrict__ aW_hh,
    const float* __restrict__ WIb, const float* __restrict__ AWIb,
    const float* __restrict__ WWIb,
    float* __restrict__ zbuf, float* __restrict__ h_state,
    float* __restrict__ cs0, float* __restrict__ cs1,
    float* __restrict__ c_buf, int* __restrict__ leaf, int* __restrict__ root,
    const int* __restrict__ cnt,
    const int* __restrict__ gpos, const int* __restrict__ gslot,
    const unsigned char* __restrict__ gmaskb,
    void* __restrict__ outp, int Km)
{
    __shared__ __align__(16) unsigned short Wz[ZB][512]; // bf16 cols of [W_hh|Ww_hh]
    __shared__ __align__(16) float Wa[HB][512];          // f32 cols of aW_hh (own h)
    __shared__ __align__(16) float hl[512];
    __shared__ __align__(16) float cinl[3][512];         // recomputed len-2 word cells
    __shared__ float wa_s[32][HB], wac_s[32][HB];
    __shared__ int vrow[32], vl2[32], l2slot[3];
    __shared__ int nv_s, l2n_s, mfmt;
    __shared__ float cprev[HB];

    const int b   = blockIdx.x;
    const int tid = threadIdx.x;
    const int wid = tid >> 6;   // wave 0..3
    const int q   = tid & 63;   // lane
    const int mode = (*cnt > NDET / 2) ? 1 : 0;

    // ---- one-time init: stage weights into LDS ----
    for (int idx = tid; idx < ZB * 512; idx += NT) {
        int c = idx % ZB, r = idx / ZB;
        int gz = b * ZB + c;
        float wv = (gz < TH3) ? ld1e(W_hh,  (size_t)r * TH3 + gz, mode)
                              : ld1e(Ww_hh, (size_t)r * TH3 + (gz - TH3), mode);
        Wz[c][r] = f2bf(wv);
    }
    for (int idx = tid; idx < HB * 512; idx += NT) {
        int ho = idx % HB, r = idx / HB;
        Wa[ho][r] = ld1e(aW_hh, (size_t)r * HD + b * HB + ho, mode);
    }
    if (tid < HB) cprev[tid] = 0.f;
    if (tid == 0) { mfmt = 0; nv_s = 0; l2n_s = 0; }
    __syncthreads();
    {   // detect mask storage: bytes at i%4!=0 nonzero => u8/bool storage
        int any = 0;
        int tot = SEQ * Km;
        for (int i = tid; i < tot; i += NT)
            if ((i & 3) && gmaskb[i]) any = 1;
        if (any) mfmt = 1;
    }
    __syncthreads();
    const int maskfmt = mfmt;
    const int* gmi = (const int*)gmaskb;

    int barn = 0;
    for (int t = 0; t < SEQ; ++t) {
        const float* crd = (t & 1) ? cs0 : cs1;   // holds c_{t-1}
        float*       cwr = (t & 1) ? cs1 : cs0;   // receives c_t
        // ================= PHASE A (consumes z = h_{t-1}@[W|Ww]) =================
        if (tid == 0) {   // gather metadata for step t
            int nv = 0, l2n = 0;
            for (int k = 0; k < Km; ++k) {
                int mv = maskfmt ? (int)gmaskb[t * Km + k] : gmi[t * Km + k];
                if (mv && nv < 32) {
                    int p = gpos[t * Km + k], sl = gslot[t * Km + k];
                    if (p < 0 || p >= t || sl < 0 || sl >= KWW) continue; // defensive
                    vrow[nv] = p * KWW + sl;
                    int li = -1;
                    if (p == t - 1 && l2n < 3) { li = l2n; l2slot[l2n] = sl; l2n++; }
                    vl2[nv] = li;
                    nv++;
                }
            }
            nv_s = nv; l2n_s = l2n;
        }
        // A1: canonical word-cell write for step t-1, own h-slice
        if (t > 0 && tid < KWW * HB) {
            int j = tid / HB, ho = tid % HB;
            int h = b * HB + ho;
            const float* wrow = WWIb + (size_t)((t - 1) * KWW + j) * TH3;
            float f  = wrow[h]            + zbuf[TH3 + h];
            float iw = wrow[HD + h]       + zbuf[TH3 + HD + h];
            float gw = wrow[2 * HD + h]   + zbuf[TH3 + 2 * HD + h];
            float ct = sigf(f) * cprev[ho] + sigf(iw) * tanhf(gw);
            c_buf[(size_t)((t - 1) * KWW + j) * HD + h] = ct;
        }
        __syncthreads();
        // A2: fully recompute len-2 word-cell rows (pos == t-1) into LDS
        for (int li = 0; li < l2n_s; ++li) {
            int sl = l2slot[li];
            const float* wrow = WWIb + (size_t)((t - 1) * KWW + sl) * TH3;
            for (int h = tid; h < HD; h += NT) {
                float f  = wrow[h]          + zbuf[TH3 + h];
                float iw = wrow[HD + h]     + zbuf[TH3 + HD + h];
                float gw = wrow[2 * HD + h] + zbuf[TH3 + 2 * HD + h];
                cinl[li][h] = sigf(f) * crd[h] + sigf(iw) * tanhf(gw);
            }
        }
        __syncthreads();
        const int nv = nv_s;
        // A3: alpha dot-products; wave 'wid' owns h = b*HB + wid
        if (nv > 0) {
            int h = b * HB + wid;
            for (int vi = 0; vi < nv; ++vi) {
                int li = vl2[vi];
                const float* cin = (li >= 0) ? cinl[li]
                                             : (c_buf + (size_t)vrow[vi] * HD);
                float4 c0  = *(const float4*)(cin + 4 * q);
                float4 c1v = *(const float4*)(cin + 256 + 4 * q);
                float4 w0  = *(const float4*)(&Wa[wid][4 * q]);
                float4 w1  = *(const float4*)(&Wa[wid][256 + 4 * q]);
                float acc = c0.x * w0.x + c0.y * w0.y + c0.z * w0.z + c0.w * w0.w
                          + c1v.x * w1.x + c1v.y * w1.y + c1v.z * w1.z + c1v.w * w1.w;
                #pragma unroll
                for (int m = 1; m < 64; m <<= 1) acc += __shfl_xor(acc, m, 64);
                if (q == 0) {
                    float alpha = sigf(AWIb[(size_t)t * HD + h] + acc);
                    float wa = expf(alpha);
                    wa_s[vi][wid]  = wa;
                    wac_s[vi][wid] = wa * cin[h];
                }
            }
        }
        __syncthreads();
        // A4: elementwise state update for own h-slice
        if (tid < HB) {
            int ho = tid, h = b * HB + ho;
            const float* wi = WIb + (size_t)t * TH3;
            float gi = sigf(zbuf[h] + wi[h]);
            float go = sigf(zbuf[HD + h] + wi[HD + h]);
            float gg = tanhf(zbuf[2 * HD + h] + wi[2 * HD + h]);
            float c1;
            if (nv > 0) {
                float wiE = expf(gi);
                float num = wiE * gg, den = wiE;
                for (int vi = 0; vi < nv; ++vi) {
                    num += wac_s[vi][ho];
                    den += wa_s[vi][ho];
                }
                c1 = num / den;
            } else {
                c1 = (1.f - gi) * cprev[ho] + gi * gg;
            }
            float h1 = go * tanhf(c1);
            cprev[ho]  = c1;
            cwr[h]     = c1;
            h_state[h] = h1;
            if (mode) {
                unsigned short* o = (unsigned short*)outp;
                o[(size_t)t * HD + h] = f2bf(h1);
                o[(size_t)SEQ * HD + (size_t)t * HD + h] = f2bf(c1);
            } else {
                float* o = (float*)outp;
                o[(size_t)t * HD + h] = h1;
                o[(size_t)SEQ * HD + (size_t)t * HD + h] = c1;
            }
        }
        gbar(leaf, root, b, ++barn);
        // ================= PHASE B: z = h_t @ [W_hh | Ww_hh] =================
        if (tid < 128)
            *(float4*)(hl + tid * 4) = *(const float4*)(h_state + tid * 4);
        __syncthreads();
        {
            float4 h0  = *(const float4*)(hl + 8 * q);
            float4 h1v = *(const float4*)(hl + 8 * q + 4);
            #pragma unroll
            for (int cc = 0; cc < 6; ++cc) {
                int c = wid * 6 + cc;
                uint4 wv = *(const uint4*)(&Wz[c][8 * q]);
                float acc = h0.x * bf2f(wv.x & 0xffffu) + h0.y * bf2f(wv.x >> 16)
                          + h0.z * bf2f(wv.y & 0xffffu) + h0.w * bf2f(wv.y >> 16)
                          + h1v.x * bf2f(wv.z & 0xffffu) + h1v.y * bf2f(wv.z >> 16)
                          + h1v.z * bf2f(wv.w & 0xffffu) + h1v.w * bf2f(wv.w >> 16);
                #pragma unroll
                for (int m = 1; m < 64; m <<= 1) acc += __shfl_xor(acc, m, 64);
                if (q == 0) zbuf[b * ZB + c] = acc;
            }
        }
        gbar(leaf, root, b, ++barn);
    }
}

extern "C" void kernel_launch(void* const* d_in, const int* in_sizes, int n_in,
                              void* d_out, int out_size, void* d_ws, size_t ws_size,
                              hipStream_t stream) {
    const void* x     = d_in[0];
    const void* W_ih  = d_in[1];
    const void* W_hh  = d_in[2];
    const void* bb    = d_in[3];
    const void* aW_ih = d_in[4];
    const void* aW_hh = d_in[5];
    const void* ab    = d_in[6];
    const void* Ww_ih = d_in[7];
    const void* Ww_hh = d_in[8];
    const void* bw    = d_in[9];
    const void* wemb  = d_in[10];
    const int* wids  = (const int*)d_in[11];
    const int* gpos  = (const int*)d_in[12];
    const int* gslot = (const int*)d_in[13];
    const unsigned char* gmask = (const unsigned char*)d_in[14];

    int Km = in_sizes[12] / SEQ;
    if (Km > 32) Km = 32;
    if (ws_size < WS_END) return;   // insufficient workspace -> fail loudly

    char* ws = (char*)d_ws;
    int*   leaf    = (int*)(ws + WS_LEAF);
    int*   root    = (int*)(ws + WS_ROOT);
    int*   flag    = (int*)(ws + WS_FLAG);
    float* zbuf    = (float*)(ws + WS_Z);
    float* cs0     = (float*)(ws + WS_CS0);
    float* cs1     = (float*)(ws + WS_CS1);
    float* h_state = (float*)(ws + WS_HSTATE);
    float* WIb     = (float*)(ws + WS_WIB);
    float* AWIb    = (float*)(ws + WS_AWIB);
    float* WWIb    = (float*)(ws + WS_WWIB);
    float* c_buf   = (float*)(ws + WS_CBUF);

    hipMemsetAsync(d_ws, 0, WS_ZEROSZ, stream);
    detect_kernel<<<1, 256, 0, stream>>>((const unsigned int*)W_ih, flag);
    gemm_bias_kernel<false><<<dim3(TH3 / 64, SEQ / 64), 256, 0, stream>>>(
        x, W_ih, bb, nullptr, flag, WIb, SEQ, TH3, HD);
    gemm_bias_kernel<false><<<dim3(HD / 64, SEQ / 64), 256, 0, stream>>>(
        x, aW_ih, ab, nullptr, flag, AWIb, SEQ, HD, HD);
    gemm_bias_kernel<true><<<dim3(TH3 / 64, (SEQ * KWW) / 64), 256, 0, stream>>>(
        wemb, Ww_ih, bw, wids, flag, WWIb, SEQ * KWW, TH3, HD);
    lattice_scan<<<GRID, NT, 0, stream>>>(
        W_hh, Ww_hh, aW_hh, WIb, AWIb, WWIb,
        zbuf, h_state, cs0, cs1, c_buf, leaf, root, flag,
        gpos, gslot, gmask, d_out, Km);
}

// Round 3
// 26024.747 us; speedup vs baseline: 3.6870x; 3.6870x over previous
//
#include <hip/hip_runtime.h>

// ---------------- problem constants ----------------
constexpr int SEQ = 2048;
constexpr int HD  = 512;     // H = D = DW
constexpr int TH3 = 1536;    // 3H
constexpr int ZT  = 3072;    // combined [W_hh | Ww_hh] output cols
constexpr int KWW = 3;

constexpr int GRID = 128;    // scan blocks
constexpr int NT   = 256;    // scan threads/block
constexpr int ZB   = ZT / GRID;   // 24 z-cols per block
constexpr int HB   = HD / GRID;   // 4 h per block
constexpr int SPB  = SEQ / GRID;  // 16 steps/block for metadata precompute
constexpr int MAXW = 16;          // max words ending at one step (Km expected ~4-8)

// ws layout (bytes)
constexpr size_t WS_LEAF   = 0;          // 8 leaf counters, 256B apart
constexpr size_t WS_ROOT   = 2048;
constexpr size_t WS_FLAG   = 2304;       // dtype-detect count
constexpr size_t WS_Z      = 4096;       // 3072 f32
constexpr size_t WS_CS0    = 16384;      // c_state ping
constexpr size_t WS_CS1    = 18432;      // c_state pong
constexpr size_t WS_HSTATE = 20480;      // 512 f32
constexpr size_t WS_ZEROSZ = 22528;      // memset region
constexpr size_t WS_WIB    = 32768;                       // 2048*1536 f32
constexpr size_t WS_AWIB   = WS_WIB  + (size_t)SEQ*TH3*4; // 2048*512 f32
constexpr size_t WS_WWIB   = WS_AWIB + (size_t)SEQ*HD*4;  // 6144*1536 f32
constexpr size_t WS_CBUF   = WS_WWIB + (size_t)SEQ*KWW*TH3*4; // 6144*512 f32
constexpr size_t WS_MHDR   = WS_CBUF + (size_t)SEQ*KWW*HD*4;  // 2048 i32
constexpr size_t WS_MROWS  = WS_MHDR + (size_t)SEQ*4;         // 2048*16 i32
constexpr size_t WS_END    = WS_MROWS + (size_t)SEQ*MAXW*4;

__device__ inline float bf2f(unsigned int u) {
    return __builtin_bit_cast(float, u << 16);
}
__device__ inline unsigned short f2bf(float f) {
    unsigned int u = __builtin_bit_cast(unsigned int, f);
    u += 0x7fffu + ((u >> 16) & 1u);   // RNE
    return (unsigned short)(u >> 16);
}
__device__ inline float sigf(float x) { return 1.0f / (1.0f + expf(-x)); }

// LLC-coherent (agent-scope, relaxed) accesses: compile to sc0/sc1-flagged
// global ops that bypass the non-coherent L1/L2 — NO wbl2/inv cache walks.
template <typename T>
__device__ inline T ldg_a(const T* p) {
    return __hip_atomic_load((T*)p, __ATOMIC_RELAXED, __HIP_MEMORY_SCOPE_AGENT);
}
template <typename T>
__device__ inline void stg_a(T* p, T v) {
    __hip_atomic_store(p, v, __ATOMIC_RELAXED, __HIP_MEMORY_SCOPE_AGENT);
}

// dual-dtype loads: mode=1 -> bf16 storage, mode=0 -> f32 storage
__device__ inline float4 ld4e(const void* p, size_t eoff, int mode) {
    if (mode) {
        uint2 v = *(const uint2*)((const unsigned short*)p + eoff);
        return make_float4(bf2f(v.x & 0xffffu), bf2f(v.x >> 16),
                           bf2f(v.y & 0xffffu), bf2f(v.y >> 16));
    }
    return *(const float4*)((const float*)p + eoff);
}
__device__ inline float ld1e(const void* p, size_t eoff, int mode) {
    return mode ? bf2f((unsigned int)((const unsigned short*)p)[eoff])
                : ((const float*)p)[eoff];
}

// ---------------- dtype detection ----------------
constexpr int NDET = 4096;
__global__ void detect_kernel(const unsigned int* __restrict__ w, int* __restrict__ cnt) {
    int local = 0;
    for (int i = threadIdx.x; i < NDET; i += 256) {
        unsigned int e = (w[i] >> 7) & 0xffu;
        if (e >= 90u && e <= 140u) local++;
    }
    atomicAdd(cnt, local);
}

// ---------------- precompute GEMM: C[M,N] = gather(A)[M,K] @ B[K,N] + bias ----------------
template<bool GATHER>
__global__ __launch_bounds__(256) void gemm_bias_kernel(
    const void* __restrict__ A, const void* __restrict__ B,
    const void* __restrict__ bias, const int* __restrict__ ids,
    const int* __restrict__ cnt,
    float* __restrict__ C, int M, int N, int K)
{
    const int mode = (*cnt > NDET / 2) ? 1 : 0;
    __shared__ __align__(16) float As[16][68];
    __shared__ __align__(16) float Bs[16][68];
    const int tid = threadIdx.x;
    const int ty = tid >> 4, tx = tid & 15;
    const int m0 = blockIdx.y * 64, n0 = blockIdx.x * 64;
    const int lrow = tid >> 2;            // 0..63
    const int kq   = (tid & 3) * 4;       // 0,4,8,12
    const int arow = m0 + lrow;
    const size_t abase = (GATHER ? (size_t)ids[arow] : (size_t)arow) * (size_t)K;
    const int brow = tid >> 4;            // 0..15
    const int bc   = (tid & 15) * 4;
    const int bcol = n0 + bc;
    float acc[4][4] = {};
    for (int k0 = 0; k0 < K; k0 += 16) {
        float4 av = ld4e(A, abase + k0 + kq, mode);
        float4 bv = ld4e(B, (size_t)(k0 + brow) * N + bcol, mode);
        As[kq + 0][lrow] = av.x;
        As[kq + 1][lrow] = av.y;
        As[kq + 2][lrow] = av.z;
        As[kq + 3][lrow] = av.w;
        Bs[brow][bc + 0] = bv.x;
        Bs[brow][bc + 1] = bv.y;
        Bs[brow][bc + 2] = bv.z;
        Bs[brow][bc + 3] = bv.w;
        __syncthreads();
        #pragma unroll
        for (int kk = 0; kk < 16; ++kk) {
            float a[4], bb[4];
            #pragma unroll
            for (int u = 0; u < 4; ++u) a[u] = As[kk][ty * 4 + u];
            #pragma unroll
            for (int v = 0; v < 4; ++v) bb[v] = Bs[kk][tx * 4 + v];
            #pragma unroll
            for (int u = 0; u < 4; ++u)
                #pragma unroll
                for (int v = 0; v < 4; ++v)
                    acc[u][v] = fmaf(a[u], bb[v], acc[u][v]);
        }
        __syncthreads();
    }
    float4 bsv = ld4e(bias, (size_t)(n0 + tx * 4), mode);
    #pragma unroll
    for (int u = 0; u < 4; ++u) {
        float4 o;
        o.x = acc[u][0] + bsv.x; o.y = acc[u][1] + bsv.y;
        o.z = acc[u][2] + bsv.z; o.w = acc[u][3] + bsv.w;
        *(float4*)(C + (size_t)(m0 + ty * 4 + u) * N + n0 + tx * 4) = o;
    }
}

// ---------------- two-level device barrier: relaxed LLC atomics only ----------------
// No __threadfence (would emit buffer_wbl2/buffer_inv L2 walks — measured ~23us/barrier).
// Correctness: all cross-block data moves via sc-flagged (agent-scope relaxed atomic)
// loads/stores whose serialization point is the LLC; each wave's s_waitcnt before
// s_barrier guarantees its stores are LLC-visible before block 0 signals arrival.
__device__ inline void gbar(int* leaf, int* root, int b, int k) {
    __atomic_signal_fence(__ATOMIC_SEQ_CST);
    __builtin_amdgcn_s_waitcnt(0);
    __syncthreads();
    if (threadIdx.x == 0) {
        int lv = __hip_atomic_fetch_add(&leaf[(b & 7) * 64], 1,
                     __ATOMIC_RELAXED, __HIP_MEMORY_SCOPE_AGENT) + 1;
        if (lv == 16 * k)
            __hip_atomic_fetch_add(root, 1, __ATOMIC_RELAXED, __HIP_MEMORY_SCOPE_AGENT);
        while (__hip_atomic_load(root, __ATOMIC_RELAXED, __HIP_MEMORY_SCOPE_AGENT) < 8 * k)
            __builtin_amdgcn_s_sleep(1);
    }
    __syncthreads();
    __atomic_signal_fence(__ATOMIC_SEQ_CST);
}

// ---------------- persistent sequential scan ----------------
__global__ __launch_bounds__(NT, 1) void lattice_scan(
    const void* __restrict__ W_hh, const void* __restrict__ Ww_hh,
    const void* __restrict__ aW_hh,
    const float* __restrict__ WIb, const float* __restrict__ AWIb,
    const float* __restrict__ WWIb,
    float* __restrict__ zbuf, float* __restrict__ h_state,
    float* __restrict__ cs0, float* __restrict__ cs1,
    float* __restrict__ c_buf, int* __restrict__ leaf, int* __restrict__ root,
    const int* __restrict__ cnt,
    const int* __restrict__ gpos, const int* __restrict__ gslot,
    const unsigned char* __restrict__ gmaskb,
    int* __restrict__ meta_hdr, int* __restrict__ meta_rows,
    void* __restrict__ outp, int Km)
{
    __shared__ __align__(16) unsigned short Wz[ZB][512]; // bf16 cols of [W_hh|Ww_hh]
    __shared__ __align__(16) float Wa[HB][512];          // f32 cols of aW_hh (own h)
    __shared__ __align__(16) float hl[512];
    __shared__ __align__(16) float zl[ZT];               // staged z for this step
    __shared__ __align__(16) float cinl[3][512];         // recomputed len-2 word cells
    __shared__ float wa_s[MAXW][HB], wac_s[MAXW][HB];
    __shared__ int vrow[MAXW], vl2[MAXW], l2slot[3];
    __shared__ int nv_s, l2n_s, mfmt;
    __shared__ float cprev[HB];

    const int b   = blockIdx.x;
    const int tid = threadIdx.x;
    const int wid = tid >> 6;   // wave 0..3
    const int q   = tid & 63;   // lane
    const int mode = (*cnt > NDET / 2) ? 1 : 0;

    // ---- one-time init: stage weights into LDS ----
    for (int idx = tid; idx < ZB * 512; idx += NT) {
        int c = idx % ZB, r = idx / ZB;
        int gz = b * ZB + c;
        float wv = (gz < TH3) ? ld1e(W_hh,  (size_t)r * TH3 + gz, mode)
                              : ld1e(Ww_hh, (size_t)r * TH3 + (gz - TH3), mode);
        Wz[c][r] = f2bf(wv);
    }
    for (int idx = tid; idx < HB * 512; idx += NT) {
        int ho = idx % HB, r = idx / HB;
        Wa[ho][r] = ld1e(aW_hh, (size_t)r * HD + b * HB + ho, mode);
    }
    if (tid < HB) cprev[tid] = 0.f;
    if (tid == 0) { mfmt = 0; nv_s = 0; l2n_s = 0; }
    __syncthreads();
    {   // detect mask storage: bytes at i%4!=0 nonzero => u8/bool storage
        int any = 0;
        int tot = SEQ * Km;
        for (int i = tid; i < tot; i += NT)
            if ((i & 3) && gmaskb[i]) any = 1;
        if (any) mfmt = 1;
    }
    __syncthreads();
    const int maskfmt = mfmt;
    const int* gmi = (const int*)gmaskb;

    // ---- one-time metadata precompute: pack per-step word list ----
    if (tid < SPB) {
        int t = b * SPB + tid;
        int nv = 0, l2n = 0, sl0 = 0, sl1 = 0, sl2 = 0;
        for (int k = 0; k < Km; ++k) {
            int mv = maskfmt ? (int)gmaskb[t * Km + k] : gmi[t * Km + k];
            if (!mv) continue;
            int p = gpos[t * Km + k], sl = gslot[t * Km + k];
            if (p < 0 || p >= t || sl < 0 || sl >= KWW) continue; // defensive
            int li = 3;
            if (p == t - 1 && l2n < 3) {
                li = l2n;
                if (l2n == 0) sl0 = sl; else if (l2n == 1) sl1 = sl; else sl2 = sl;
                l2n++;
            }
            if (nv < MAXW) {
                stg_a(&meta_rows[t * MAXW + nv], (p * KWW + sl) | (li << 16));
                nv++;
            }
        }
        stg_a(&meta_hdr[t], nv | (l2n << 5) | (sl0 << 8) | (sl1 << 10) | (sl2 << 12));
    }

    int barn = 0;
    gbar(leaf, root, b, ++barn);   // publish metadata

    for (int t = 0; t < SEQ; ++t) {
        const float* crd = (t & 1) ? cs0 : cs1;   // holds c_{t-1}
        float*       cwr = (t & 1) ? cs1 : cs0;   // receives c_t
        // ============ PHASE A (consumes z = h_{t-1}@[W|Ww]) ============
        // stage z into LDS (one LLC roundtrip) + unpack metadata
        for (int i = tid; i < ZT; i += NT) zl[i] = ldg_a(zbuf + i);
        if (tid == 0) {
            int hdr = meta_hdr[t];                // immutable after init barrier
            int nv = hdr & 31, l2n = (hdr >> 5) & 3;
            l2slot[0] = (hdr >> 8) & 3; l2slot[1] = (hdr >> 10) & 3;
            l2slot[2] = (hdr >> 12) & 3;
            for (int i = 0; i < nv; ++i) {
                int e = meta_rows[t * MAXW + i];
                vrow[i] = e & 0xffff;
                int li = (e >> 16) & 3;
                vl2[i] = (li == 3) ? -1 : li;
            }
            nv_s = nv; l2n_s = l2n;
        }
        __syncthreads();
        // A1: canonical word-cell write for step t-1, own h-slice
        if (t > 0 && tid < KWW * HB) {
            int j = tid / HB, ho = tid % HB;
            int h = b * HB + ho;
            const float* wrow = WWIb + (size_t)((t - 1) * KWW + j) * TH3;
            float f  = wrow[h]          + zl[TH3 + h];
            float iw = wrow[HD + h]     + zl[TH3 + HD + h];
            float gw = wrow[2 * HD + h] + zl[TH3 + 2 * HD + h];
            float ct = sigf(f) * cprev[ho] + sigf(iw) * tanhf(gw);
            stg_a(&c_buf[(size_t)((t - 1) * KWW + j) * HD + h], ct);
        }
        // A2: recompute len-2 word-cell rows (pos == t-1) into LDS
        for (int li = 0; li < l2n_s; ++li) {
            int sl = l2slot[li];
            const float* wrow = WWIb + (size_t)((t - 1) * KWW + sl) * TH3;
            for (int h = tid; h < HD; h += NT) {
                float f  = wrow[h]          + zl[TH3 + h];
                float iw = wrow[HD + h]     + zl[TH3 + HD + h];
                float gw = wrow[2 * HD + h] + zl[TH3 + 2 * HD + h];
                cinl[li][h] = sigf(f) * ldg_a(crd + h) + sigf(iw) * tanhf(gw);
            }
        }
        __syncthreads();
        const int nv = nv_s;
        // A3: alpha dot-products; wave 'wid' owns h = b*HB + wid
        if (nv > 0) {
            int h = b * HB + wid;
            for (int vi = 0; vi < nv; ++vi) {
                int li = vl2[vi];
                const float* cin = (li >= 0) ? cinl[li]
                                             : (c_buf + (size_t)vrow[vi] * HD);
                float4 c0  = *(const float4*)(cin + 4 * q);
                float4 c1v = *(const float4*)(cin + 256 + 4 * q);
                float4 w0  = *(const float4*)(&Wa[wid][4 * q]);
                float4 w1  = *(const float4*)(&Wa[wid][256 + 4 * q]);
                float acc = c0.x * w0.x + c0.y * w0.y + c0.z * w0.z + c0.w * w0.w
                          + c1v.x * w1.x + c1v.y * w1.y + c1v.z * w1.z + c1v.w * w1.w;
                #pragma unroll
                for (int m = 1; m < 64; m <<= 1) acc += __shfl_xor(acc, m, 64);
                if (q == 0) {
                    float alpha = sigf(AWIb[(size_t)t * HD + h] + acc);
                    float wa = expf(alpha);
                    wa_s[vi][wid]  = wa;
                    wac_s[vi][wid] = wa * cin[h];
                }
            }
        }
        __syncthreads();
        // A4: elementwise state update for own h-slice
        if (tid < HB) {
            int ho = tid, h = b * HB + ho;
            const float* wi = WIb + (size_t)t * TH3;
            float gi = sigf(zl[h] + wi[h]);
            float go = sigf(zl[HD + h] + wi[HD + h]);
            float gg = tanhf(zl[2 * HD + h] + wi[2 * HD + h]);
            float c1;
            if (nv > 0) {
                float wiE = expf(gi);
                float num = wiE * gg, den = wiE;
                for (int vi = 0; vi < nv; ++vi) {
                    num += wac_s[vi][ho];
                    den += wa_s[vi][ho];
                }
                c1 = num / den;
            } else {
                c1 = (1.f - gi) * cprev[ho] + gi * gg;
            }
            float h1 = go * tanhf(c1);
            cprev[ho] = c1;
            stg_a(&cwr[h], c1);
            stg_a(&h_state[h], h1);
            if (mode) {
                unsigned short* o = (unsigned short*)outp;
                o[(size_t)t * HD + h] = f2bf(h1);
                o[(size_t)SEQ * HD + (size_t)t * HD + h] = f2bf(c1);
            } else {
                float* o = (float*)outp;
                o[(size_t)t * HD + h] = h1;
                o[(size_t)SEQ * HD + (size_t)t * HD + h] = c1;
            }
        }
        gbar(leaf, root, b, ++barn);
        // ============ PHASE B: z = h_t @ [W_hh | Ww_hh] ============
        for (int i = tid; i < HD; i += NT) hl[i] = ldg_a(h_state + i);
        __syncthreads();
        {
            float4 h0  = *(const float4*)(hl + 8 * q);
            float4 h1v = *(const float4*)(hl + 8 * q + 4);
            #pragma unroll
            for (int cc = 0; cc < 6; ++cc) {
                int c = wid * 6 + cc;
                uint4 wv = *(const uint4*)(&Wz[c][8 * q]);
                float acc = h0.x * bf2f(wv.x & 0xffffu) + h0.y * bf2f(wv.x >> 16)
                          + h0.z * bf2f(wv.y & 0xffffu) + h0.w * bf2f(wv.y >> 16)
                          + h1v.x * bf2f(wv.z & 0xffffu) + h1v.y * bf2f(wv.z >> 16)
                          + h1v.z * bf2f(wv.w & 0xffffu) + h1v.w * bf2f(wv.w >> 16);
                #pragma unroll
                for (int m = 1; m < 64; m <<= 1) acc += __shfl_xor(acc, m, 64);
                if (q == 0) stg_a(&zbuf[b * ZB + c], acc);
            }
        }
        gbar(leaf, root, b, ++barn);
    }
}

extern "C" void kernel_launch(void* const* d_in, const int* in_sizes, int n_in,
                              void* d_out, int out_size, void* d_ws, size_t ws_size,
                              hipStream_t stream) {
    const void* x     = d_in[0];
    const void* W_ih  = d_in[1];
    const void* W_hh  = d_in[2];
    const void* bb    = d_in[3];
    const void* aW_ih = d_in[4];
    const void* aW_hh = d_in[5];
    const void* ab    = d_in[6];
    const void* Ww_ih = d_in[7];
    const void* Ww_hh = d_in[8];
    const void* bw    = d_in[9];
    const void* wemb  = d_in[10];
    const int* wids  = (const int*)d_in[11];
    const int* gpos  = (const int*)d_in[12];
    const int* gslot = (const int*)d_in[13];
    const unsigned char* gmask = (const unsigned char*)d_in[14];

    int Km = in_sizes[12] / SEQ;
    if (Km > 32) Km = 32;
    if (ws_size < WS_END) return;   // insufficient workspace -> fail loudly

    char* ws = (char*)d_ws;
    int*   leaf    = (int*)(ws + WS_LEAF);
    int*   root    = (int*)(ws + WS_ROOT);
    int*   flag    = (int*)(ws + WS_FLAG);
    float* zbuf    = (float*)(ws + WS_Z);
    float* cs0     = (float*)(ws + WS_CS0);
    float* cs1     = (float*)(ws + WS_CS1);
    float* h_state = (float*)(ws + WS_HSTATE);
    float* WIb     = (float*)(ws + WS_WIB);
    float* AWIb    = (float*)(ws + WS_AWIB);
    float* WWIb    = (float*)(ws + WS_WWIB);
    float* c_buf   = (float*)(ws + WS_CBUF);
    int*   mhdr    = (int*)(ws + WS_MHDR);
    int*   mrows   = (int*)(ws + WS_MROWS);

    hipMemsetAsync(d_ws, 0, WS_ZEROSZ, stream);
    detect_kernel<<<1, 256, 0, stream>>>((const unsigned int*)W_ih, flag);
    gemm_bias_kernel<false><<<dim3(TH3 / 64, SEQ / 64), 256, 0, stream>>>(
        x, W_ih, bb, nullptr, flag, WIb, SEQ, TH3, HD);
    gemm_bias_kernel<false><<<dim3(HD / 64, SEQ / 64), 256, 0, stream>>>(
        x, aW_ih, ab, nullptr, flag, AWIb, SEQ, HD, HD);
    gemm_bias_kernel<true><<<dim3(TH3 / 64, (SEQ * KWW) / 64), 256, 0, stream>>>(
        wemb, Ww_ih, bw, wids, flag, WWIb, SEQ * KWW, TH3, HD);
    lattice_scan<<<GRID, NT, 0, stream>>>(
        W_hh, Ww_hh, aW_hh, WIb, AWIb, WWIb,
        zbuf, h_state, cs0, cs1, c_buf, leaf, root, flag,
        gpos, gslot, gmask, mhdr, mrows, d_out, Km);
}